// Round 1
// baseline (344.715 us; speedup 1.0000x reference)
//
#include <hip/hip_runtime.h>

#define TT 1024
#define NB 4096
#define HH 50
#define DTC 0.1f

typedef __attribute__((ext_vector_type(8))) short short8;
typedef __attribute__((ext_vector_type(4))) float float4v;
typedef __attribute__((ext_vector_type(4))) unsigned short ushort4v;

__device__ __forceinline__ unsigned short f2bf(float f) {
    unsigned int u = __builtin_bit_cast(unsigned int, f);
    u += 0x7FFFu + ((u >> 16) & 1u);   // round-to-nearest-even
    return (unsigned short)(u >> 16);
}

__device__ __forceinline__ float one_plus_tanh(float h) {
    // 1 + tanh(h) = 2e/(e+1), e = exp2(2*log2(e)*h). |h| stays O(1) -> no overflow.
    float e = __builtin_amdgcn_exp2f(2.8853900817779268f * h);
    return (e + e) * __builtin_amdgcn_rcpf(e + 1.0f);
}

// Builds: out0[b] = Jout@h0 (column b), jin_aug[64] (Jin, c_in=Jout@Jin at 50),
// Aaug 64x64 bf16: rows 0..49 = [Jrec | bias | 0], row 50 = [Jout@Jrec | Jout@bias | 0].
__global__ void setup_kernel(const float* __restrict__ Jin,
                             const float* __restrict__ Jrec,
                             const float* __restrict__ Jout,
                             const float* __restrict__ bias,
                             const float* __restrict__ h0,
                             float* __restrict__ out0,
                             float* __restrict__ jin_aug,
                             unsigned short* __restrict__ Aaug) {
    const int tid = threadIdx.x;
    const int blk = blockIdx.x;
    if (blk < 16) {
        const int col = blk * 256 + tid;
        float s = 0.f;
        for (int i = 0; i < HH; ++i) s += Jout[i] * h0[i * NB + col];
        out0[col] = s;
    } else {
        for (int idx = tid; idx < 64 * 64; idx += 256) {
            const int row = idx >> 6, k = idx & 63;
            float v = 0.f;
            if (row < HH) {
                if (k < HH) v = Jrec[row * HH + k];
                else if (k == HH) v = bias[row];
            } else if (row == HH) {
                if (k < HH) {
                    float s = 0.f;
                    for (int i = 0; i < HH; ++i) s += Jout[i] * Jrec[i * HH + k];
                    v = s;
                } else if (k == HH) {
                    float s = 0.f;
                    for (int i = 0; i < HH; ++i) s += Jout[i] * bias[i];
                    v = s;
                }
            }
            Aaug[idx] = f2bf(v);
        }
        if (tid < 64) {
            float v = 0.f;
            if (tid < HH) v = Jin[tid];
            else if (tid == HH) {
                float s = 0.f;
                for (int i = 0; i < HH; ++i) s += Jout[i] * Jin[i];
                v = s;
            }
            jin_aug[tid] = v;
        }
    }
}

// 256 blocks (16 cols each) x 256 threads (4 waves; wave w = M-tile rows 16w..16w+15).
// h state in fp32 C-layout regs (row = 16w+4q+r, col = lane&15). Row 50 carries out_t.
// r = 1+tanh(h) round-trips LDS (double-buffered, B-operand order), 1 barrier/step.
__global__ void __launch_bounds__(256) rnn_kernel(
        const float* __restrict__ x,
        const float* __restrict__ h0,
        const float* __restrict__ out0,
        const float* __restrict__ jin_aug,
        const unsigned short* __restrict__ Aaug,
        float* __restrict__ out) {
    __shared__ unsigned short rbuf[2][16][72];   // [buf][n][k], stride 72 for banking

    const int tid  = threadIdx.x;
    const int w    = tid >> 6;     // wave id = M-tile index
    const int lane = tid & 63;
    const int n    = lane & 15;    // column within tile (A-row / B-col / C-col field)
    const int q    = lane >> 4;    // quad
    const int col  = (blockIdx.x << 4) + n;
    const int row0 = 16 * w + 4 * q;   // C rows handled by this lane: row0..row0+3

    // A fragments: A[m = 16w + (lane&15)][k = 8q+j (+32)]
    short8 a0, a1;
    {
        const unsigned short* ap = Aaug + ((16 * w + n) << 6) + (q << 3);
        a0 = *(const short8*)ap;
        a1 = *(const short8*)(ap + 32);
    }

    float jin[4], h[4];
#pragma unroll
    for (int r = 0; r < 4; ++r) {
        jin[r] = jin_aug[row0 + r];                       // 0 for rows > 50
        h[r] = (row0 + r < HH) ? h0[(row0 + r) * NB + col] : 0.f;
    }
    const bool outlane = (w == 3) && (q == 0);            // holds row 50 in h[2]
    if (outlane) h[2] = out0[col];                        // out_{-1} = Jout@h0

    // initial r(t=0) into buffer 0
    {
        ushort4v pk;
#pragma unroll
        for (int r = 0; r < 4; ++r) {
            float rv = one_plus_tanh(h[r]);
            if (r == 2 && outlane) rv = 1.0f;             // r_aug[50] = 1 (bias column)
            pk[r] = f2bf(rv);
        }
        *(ushort4v*)&rbuf[0][n][row0] = pk;
    }

    const unsigned short* rp[2] = { &rbuf[0][n][q << 3], &rbuf[1][n][q << 3] };
    unsigned short* wp[2] = { &rbuf[0][n][row0], &rbuf[1][n][row0] };

    float xv = x[col];     // x_0 prefetched
    __syncthreads();

#pragma unroll 2
    for (int t = 0; t < TT; ++t) {
        const int buf = t & 1;
        // B-frags: contiguous k (same slot-permutation as A-frags -> exact contraction)
        short8 b0 = *(const short8*)(rp[buf]);
        short8 b1 = *(const short8*)(rp[buf] + 32);

        // prefetch next x while LDS/MFMA latency drains
        const int tn = (t + 1 < TT) ? t + 1 : t;
        float xn = x[tn * NB + col];

        float4v acc = {0.f, 0.f, 0.f, 0.f};
        acc = __builtin_amdgcn_mfma_f32_16x16x32_bf16(a0, b0, acc, 0, 0, 0);
        acc = __builtin_amdgcn_mfma_f32_16x16x32_bf16(a1, b1, acc, 0, 0, 0);

        const float dtx = DTC * xv;
#pragma unroll
        for (int r = 0; r < 4; ++r)
            h[r] = (1.0f - DTC) * h[r] + DTC * acc[r] + dtx * jin[r];

        if (outlane) out[t * NB + col] = h[2];            // row 50 == out_t

        ushort4v pk;
#pragma unroll
        for (int r = 0; r < 4; ++r) {
            float rv = one_plus_tanh(h[r]);
            if (r == 2 && outlane) rv = 1.0f;
            pk[r] = f2bf(rv);
        }
        *(ushort4v*)wp[buf ^ 1] = pk;

        xv = xn;
        __syncthreads();
    }
}

extern "C" void kernel_launch(void* const* d_in, const int* in_sizes, int n_in,
                              void* d_out, int out_size, void* d_ws, size_t ws_size,
                              hipStream_t stream) {
    (void)in_sizes; (void)n_in; (void)out_size; (void)ws_size;
    const float* x    = (const float*)d_in[0];
    const float* Jin  = (const float*)d_in[1];
    const float* Jrec = (const float*)d_in[2];
    const float* Jout = (const float*)d_in[3];
    const float* bias = (const float*)d_in[4];
    const float* h0   = (const float*)d_in[5];
    float* out = (float*)d_out;

    float* ws_out0 = (float*)d_ws;                          // 4096 f
    float* ws_jin  = ws_out0 + NB;                          // 64 f
    unsigned short* ws_A = (unsigned short*)(ws_jin + 64);  // 4096 us (16B aligned)

    hipLaunchKernelGGL(setup_kernel, dim3(17), dim3(256), 0, stream,
                       Jin, Jrec, Jout, bias, h0, ws_out0, ws_jin, ws_A);
    hipLaunchKernelGGL(rnn_kernel, dim3(256), dim3(256), 0, stream,
                       x, h0, ws_out0, ws_jin, ws_A, out);
}

// Round 2
// 316.942 us; speedup vs baseline: 1.0876x; 1.0876x over previous
//
#include <hip/hip_runtime.h>

#define TT 1024
#define NB 4096
#define HH 50
#define DTC 0.1f
#define NL2E2 -2.8853900817779268f   // -2*log2(e)

typedef __attribute__((ext_vector_type(8))) short short8;
typedef __attribute__((ext_vector_type(4))) float float4v;
typedef __attribute__((ext_vector_type(2))) unsigned int uint2v;

__device__ __forceinline__ unsigned short f2bf(float f) {
    unsigned int u = __builtin_bit_cast(unsigned int, f);
    u += 0x7FFFu + ((u >> 16) & 1u);   // RNE
    return (unsigned short)(u >> 16);
}

// Raw barrier: order LDS only; leave global loads/stores in flight (no vmcnt drain).
#define BAR() __asm__ volatile("s_waitcnt lgkmcnt(0)\n\ts_barrier" ::: "memory")

// A_aug 64x64 bf16, dt and the sigmoid 1/2 folded in:
//   rows 0..49:  [0.2*Jrec | 0.1*bias | 0.1*Jin | 0]
//   row  50:     [0.2*Jout@Jrec | 0.1*Jout@bias | 0.1*Jout@Jin | 0]   (out recurrence)
// B-slots per step: rows 0..49 = sigmoid(2h)=(1+tanh h)/2, row 50 = 1, row 51 = x_t.
// Then h_next = 0.9*h + A_aug @ r'  reproduces the reference exactly.
__global__ void setup_kernel(const float* __restrict__ Jin,
                             const float* __restrict__ Jrec,
                             const float* __restrict__ Jout,
                             const float* __restrict__ bias,
                             const float* __restrict__ h0,
                             float* __restrict__ out0,
                             unsigned short* __restrict__ Aaug) {
    const int tid = threadIdx.x;
    const int blk = blockIdx.x;
    if (blk < 16) {
        const int col = blk * 256 + tid;
        float s = 0.f;
        for (int i = 0; i < HH; ++i) s += Jout[i] * h0[i * NB + col];
        out0[col] = s;
    } else {
        for (int idx = tid; idx < 64 * 64; idx += 256) {
            const int row = idx >> 6, k = idx & 63;
            float v = 0.f;
            if (row < HH) {
                if (k < HH)           v = 2.0f * DTC * Jrec[row * HH + k];
                else if (k == HH)     v = DTC * bias[row];
                else if (k == HH + 1) v = DTC * Jin[row];
            } else if (row == HH) {
                if (k < HH) {
                    float s = 0.f;
                    for (int i = 0; i < HH; ++i) s += Jout[i] * Jrec[i * HH + k];
                    v = 2.0f * DTC * s;
                } else if (k == HH) {
                    float s = 0.f;
                    for (int i = 0; i < HH; ++i) s += Jout[i] * bias[i];
                    v = DTC * s;
                } else if (k == HH + 1) {
                    float s = 0.f;
                    for (int i = 0; i < HH; ++i) s += Jout[i] * Jin[i];
                    v = DTC * s;
                }
            }
            Aaug[idx] = f2bf(v);
        }
    }
}

// 256 blocks x 256 threads; wave w = M-tile rows 16w..16w+15, block = 16 batch cols.
// h in fp32 C-layout regs (row = 16w+4q+reg, col = lane&15). Row 50 carries out_t.
__global__ void __launch_bounds__(256) rnn_kernel(
        const float* __restrict__ x,
        const float* __restrict__ h0,
        const float* __restrict__ out0,
        const unsigned short* __restrict__ Aaug,
        float* __restrict__ out) {
    __shared__ unsigned short rbuf[2][16][72];

    const int tid  = threadIdx.x;
    const int w    = tid >> 6;
    const int lane = tid & 63;
    const int n    = lane & 15;
    const int q    = lane >> 4;
    const int col  = (blockIdx.x << 4) + n;
    const int row0 = 16 * w + 4 * q;

    // A fragments, contiguous our-k (slot permutation cancels between A and B frags)
    short8 a0, a1;
    {
        const unsigned short* ap = Aaug + ((16 * w + n) << 6) + (q << 3);
        a0 = *(const short8*)ap;
        a1 = *(const short8*)(ap + 32);
    }

    float h[4];
#pragma unroll
    for (int r = 0; r < 4; ++r)
        h[r] = (row0 + r < HH) ? h0[(row0 + r) * NB + col] : 0.f;
    const bool outlane = (w == 3) && (q == 0);   // regs: 48,49,out(50),x-slot(51)
    if (outlane) h[2] = out0[col];

    const float* xp = x + col;
    float* outp = out + col;

    // x prefetch chain, depth 3 (covers HBM cold-miss latency ~900cy)
    float xw = 0.f, xn1 = 0.f, xn2 = 0.f;
    if (outlane) { xw = xp[0]; xn1 = xp[NB]; xn2 = xp[2 * NB]; }

    // initial r'(h0) into buffer 0
    {
        unsigned int u[4];
#pragma unroll
        for (int r = 0; r < 4; ++r) {
            float e = __builtin_amdgcn_exp2f(NL2E2 * h[r]);
            float rv = __builtin_amdgcn_rcpf(1.0f + e);
            u[r] = __builtin_bit_cast(unsigned int, rv);
        }
        if (outlane) { u[2] = 0x3F800000u; u[3] = __builtin_bit_cast(unsigned int, xw); }
#pragma unroll
        for (int r = 0; r < 4; ++r) u[r] += 0x8000u;
        uint2v pk;
        pk[0] = __builtin_amdgcn_perm(u[1], u[0], 0x07060302u);
        pk[1] = __builtin_amdgcn_perm(u[3], u[2], 0x07060302u);
        *(uint2v*)&rbuf[0][n][row0] = pk;
    }

    unsigned short* wr[2] = { &rbuf[0][n][row0], &rbuf[1][n][row0] };
    const unsigned short* rd[2] = { &rbuf[0][n][q << 3], &rbuf[1][n][q << 3] };

    __syncthreads();   // one-time full sync (drains prefetches once; fine)

#pragma unroll 2
    for (int t = 0; t < TT; ++t) {
        const int buf = t & 1;
        short8 b0 = *(const short8*)(rd[buf]);
        short8 b1 = *(const short8*)(rd[buf] + 32);

        // prefetch x_{t+3}
        float xf = 0.f;
        if (outlane) {
            int tt = (t + 3 < TT) ? t + 3 : TT - 1;
            xf = xp[tt * NB];
        }

        float4v acc = {0.f, 0.f, 0.f, 0.f};
        acc = __builtin_amdgcn_mfma_f32_16x16x32_bf16(a0, b0, acc, 0, 0, 0);
        acc = __builtin_amdgcn_mfma_f32_16x16x32_bf16(a1, b1, acc, 0, 0, 0);

#pragma unroll
        for (int r = 0; r < 4; ++r)
            h[r] = __builtin_fmaf(h[r], 1.0f - DTC, acc[r]);

        // r' = sigmoid(2h); special slots: row50=1, row51=x_{t+1}
        unsigned int u[4];
#pragma unroll
        for (int r = 0; r < 4; ++r) {
            float e = __builtin_amdgcn_exp2f(NL2E2 * h[r]);
            float rv = __builtin_amdgcn_rcpf(1.0f + e);
            u[r] = __builtin_bit_cast(unsigned int, rv);
        }
        if (outlane) { u[2] = 0x3F800000u; u[3] = __builtin_bit_cast(unsigned int, xn1); }
#pragma unroll
        for (int r = 0; r < 4; ++r) u[r] += 0x8000u;   // round-half-up to bf16
        uint2v pk;
        pk[0] = __builtin_amdgcn_perm(u[1], u[0], 0x07060302u);
        pk[1] = __builtin_amdgcn_perm(u[3], u[2], 0x07060302u);
        *(uint2v*)wr[buf ^ 1] = pk;

        if (outlane) outp[t * NB] = h[2];   // out_t, off the barrier path

        xn1 = xn2; xn2 = xf;
        BAR();
    }
}

extern "C" void kernel_launch(void* const* d_in, const int* in_sizes, int n_in,
                              void* d_out, int out_size, void* d_ws, size_t ws_size,
                              hipStream_t stream) {
    (void)in_sizes; (void)n_in; (void)out_size; (void)ws_size;
    const float* x    = (const float*)d_in[0];
    const float* Jin  = (const float*)d_in[1];
    const float* Jrec = (const float*)d_in[2];
    const float* Jout = (const float*)d_in[3];
    const float* bias = (const float*)d_in[4];
    const float* h0   = (const float*)d_in[5];
    float* out = (float*)d_out;

    float* ws_out0 = (float*)d_ws;                            // 4096 f32
    unsigned short* ws_A = (unsigned short*)(ws_out0 + NB);   // 4096 bf16, 16B aligned

    hipLaunchKernelGGL(setup_kernel, dim3(17), dim3(256), 0, stream,
                       Jin, Jrec, Jout, bias, h0, ws_out0, ws_A);
    hipLaunchKernelGGL(rnn_kernel, dim3(256), dim3(256), 0, stream,
                       x, h0, ws_out0, ws_A, out);
}